// Round 1
// baseline (453.003 us; speedup 1.0000x reference)
//
#include <hip/hip_runtime.h>
#include <math.h>

#define Lc 13
#define Hc 1024
#define Bc 32
#define Sc 2048
#define BSc (Bc*Sc)
#define HT 64
#define NT (Hc/HT)
#define RPB 64
#define CHUNK 128
#define NCHUNK 16

#define INV_LN2 1.44269504088896340736f
#define LN2f    0.69314718055994530942f

#if __has_builtin(__builtin_amdgcn_exp2f)
#define EXP2F(x) __builtin_amdgcn_exp2f(x)
#else
#define EXP2F(x) exp2f(x)
#endif
#if __has_builtin(__builtin_amdgcn_logf)
#define LOG2F(x) __builtin_amdgcn_logf(x)
#else
#define LOG2F(x) log2f(x)
#endif

// ---------------------------------------------------------------------------
// Kernel A: logits[b,s,l] = sum_h hs[b,s,h]*W[l,h] + bias[l]
// 64 threads/block, 64 rows/block, h-tiled by 64 through LDS.
// LDS dest of global_load_lds must be linear -> pre-swizzle the GLOBAL source
// (G21); compute reads apply the same XOR swizzle (bank-conflict-free b128).
// W access is wave-uniform -> scalar loads (no LDS traffic for W).
// ---------------------------------------------------------------------------
__global__ void k_logits(const float* __restrict__ A, const float* __restrict__ W,
                         const float* __restrict__ bias, float* __restrict__ out) {
  __shared__ float tile[RPB * HT];   // 16 KB
  const int tid = threadIdx.x;
  const int rowBase = blockIdx.x * RPB;

  float acc[Lc];
#pragma unroll
  for (int l = 0; l < Lc; ++l) acc[l] = bias[l];

  for (int ht = 0; ht < NT; ++ht) {
    __syncthreads();   // WAR: previous compute done before restage
#pragma unroll
    for (int k = 0; k < 16; ++k) {
      int slot = k * 64 + tid;            // 16B slots, lane-contiguous
      int row  = slot >> 4;               // 16 slots per row
      int h4   = (slot & 15) ^ (row & 7); // inverse swizzle on the source
      const float* gp = A + ((size_t)(rowBase + row) * Hc + (size_t)ht * HT + h4 * 4);
      float* lp = &tile[k * 64 * 4];      // wave-uniform base (block == 1 wave)
      __builtin_amdgcn_global_load_lds(
          (const __attribute__((address_space(1))) void*)gp,
          (__attribute__((address_space(3))) void*)lp, 16, 0, 0);
    }
    __syncthreads();   // drains vmcnt incl. global_load_lds

    const float4* W4 = (const float4*)W;
#pragma unroll
    for (int h4 = 0; h4 < 16; ++h4) {
      // swizzled read: row=tid, data h4 lives at slot h4^(row&7)
      float4 a = *(const float4*)&tile[tid * HT + ((h4 * 4) ^ ((tid & 7) << 2))];
#pragma unroll
      for (int l = 0; l < Lc; ++l) {
        float4 w = W4[l * (Hc / 4) + ht * (HT / 4) + h4];  // uniform -> s_load
        acc[l] += a.x * w.x + a.y * w.y + a.z * w.z + a.w * w.w;
      }
    }
  }
  size_t o = (size_t)(rowBase + tid) * Lc;
#pragma unroll
  for (int l = 0; l < Lc; ++l) out[o + l] = acc[l];
}

// ---------------------------------------------------------------------------
// Kernel B: per (batch, chunk) 13x13 log-semiring transfer matrix.
// Block = 256 threads: 16 groups of 16 lanes; group g = row i, lane k = col.
// M'[i,k] = e_t[k] + lse2_j(M[i,j] + T2[j,k]); masked step = identity (skip).
// All scores kept in log2 domain (native v_exp/v_log).
// ---------------------------------------------------------------------------
__global__ void k_chunks(const float* __restrict__ logits, const int* __restrict__ mask,
                         const float* __restrict__ T, float* __restrict__ Mout) {
  const int bp = blockIdx.x;
  const int b  = bp >> 4;       // NCHUNK == 16
  const int p  = bp & 15;
  const int tid = threadIdx.x;
  const int g = tid >> 4;
  const int k = tid & 15;
  const int kk = (k < 13) ? k : 0;
  const int gg = (g < 13) ? g : 0;
  const bool active = (g < 13) && (k < 13);

  float Tc[13];   // column k of T, log2 domain
#pragma unroll
  for (int j = 0; j < 13; ++j) Tc[j] = T[j * 13 + kk] * INV_LN2;

  const int t0 = 1 + p * CHUNK;
  const int t1 = min(t0 + CHUNK, Sc);
  const size_t lbase = (size_t)b * Sc;

  // first step of the chunk initializes M
  float e0 = logits[(lbase + t0) * Lc + kk] * INV_LN2;
  int   m0 = mask[lbase + t0];
  float Tik = T[gg * 13 + kk] * INV_LN2;           // direct load (no dyn array idx)
  float M = m0 ? (Tik + e0) : ((g == k) ? 0.f : -1e30f);

  for (int t = t0 + 1; t < t1; ++t) {
    float e  = logits[(lbase + t) * Lc + kk] * INV_LN2;
    int   mk = mask[lbase + t];
    float v[13];
#pragma unroll
    for (int j = 0; j < 13; ++j) v[j] = __shfl(M, j, 16) + Tc[j];
    float m01 = fmaxf(v[0], v[1]),  m23 = fmaxf(v[2], v[3]);
    float m45 = fmaxf(v[4], v[5]),  m67 = fmaxf(v[6], v[7]);
    float m89 = fmaxf(v[8], v[9]),  mab = fmaxf(v[10], v[11]);
    float mx = fmaxf(fmaxf(fmaxf(m01, m23), fmaxf(m45, m67)),
                     fmaxf(fmaxf(m89, mab), v[12]));
    float e0s = EXP2F(v[0] - mx) + EXP2F(v[1] - mx);
    float e1s = EXP2F(v[2] - mx) + EXP2F(v[3] - mx);
    float e2s = EXP2F(v[4] - mx) + EXP2F(v[5] - mx);
    float e3s = EXP2F(v[6] - mx) + EXP2F(v[7] - mx);
    float e4s = EXP2F(v[8] - mx) + EXP2F(v[9] - mx);
    float e5s = EXP2F(v[10] - mx) + EXP2F(v[11] - mx);
    float s = ((e0s + e1s) + (e2s + e3s)) + ((e4s + e5s) + EXP2F(v[12] - mx));
    float nM = e + mx + LOG2F(s);
    M = mk ? nM : M;
  }
  if (active) Mout[(size_t)bp * 169 + g * 13 + k] = M;
}

// ---------------------------------------------------------------------------
// Kernel C: per batch: combine chunk matrices -> denominator; numerator; loss.
// One wave per batch.
// ---------------------------------------------------------------------------
__global__ void k_final(const float* __restrict__ logits, const int* __restrict__ mask,
                        const int* __restrict__ labels, const float* __restrict__ startT,
                        const float* __restrict__ endT, const float* __restrict__ T,
                        const float* __restrict__ Mws, float* __restrict__ out0) {
  const int b = blockIdx.x;
  const int lane = threadIdx.x;
  const int kk = (lane < 13) ? lane : 0;
  const size_t lbase = (size_t)b * Sc;

  // ---- denominator (log2 domain) ----
  float v = (startT[kk] + logits[lbase * Lc + kk]) * INV_LN2;
  for (int p = 0; p < NCHUNK; ++p) {
    const float* Mp = Mws + (size_t)(b * NCHUNK + p) * 169;
    float a[13];
#pragma unroll
    for (int j = 0; j < 13; ++j) a[j] = __shfl(v, j, 64) + Mp[j * 13 + kk];
    float mx = a[0];
#pragma unroll
    for (int j = 1; j < 13; ++j) mx = fmaxf(mx, a[j]);
    float s = 0.f;
#pragma unroll
    for (int j = 0; j < 13; ++j) s += EXP2F(a[j] - mx);
    v = mx + LOG2F(s);
  }
  float x = (lane < 13) ? (v + endT[kk] * INV_LN2) : -1e30f;
  float mx = x;
#pragma unroll
  for (int off = 1; off < 16; off <<= 1) mx = fmaxf(mx, __shfl_xor(mx, off, 16));
  float sx = EXP2F(x - mx);
#pragma unroll
  for (int off = 1; off < 16; off <<= 1) sx += __shfl_xor(sx, off, 16);
  float den = (mx + LOG2F(sx)) * LN2f;   // valid on lanes 0..15; use lane 0

  // ---- numerator ----
  float np = 0.f;
  int   sl = 0;
  for (int t = lane; t < Sc; t += 64) {
    int mk = mask[lbase + t];
    sl += mk;
    int tg = labels[lbase + t];
    float em = logits[(lbase + t) * Lc + tg];
    if (t == 0) {
      np += startT[tg] + em;
    } else if (mk) {
      np += T[labels[lbase + t - 1] * 13 + tg] + em;
    }
  }
#pragma unroll
  for (int off = 32; off; off >>= 1) {
    np += __shfl_xor(np, off, 64);
    sl += __shfl_xor(sl, off, 64);
  }
  if (lane == 0) {
    int lastTag = labels[lbase + sl - 1];
    float num = np + endT[lastTag];
    float llh = num - den;
    atomicAdd(out0, -llh * (1.0f / Bc));
  }
}

extern "C" void kernel_launch(void* const* d_in, const int* in_sizes, int n_in,
                              void* d_out, int out_size, void* d_ws, size_t ws_size,
                              hipStream_t stream) {
  const float* hs     = (const float*)d_in[0];
  const int*   amask  = (const int*)d_in[1];
  const int*   labels = (const int*)d_in[2];
  const float* W      = (const float*)d_in[3];
  const float* bias   = (const float*)d_in[4];
  const float* startT = (const float*)d_in[5];
  const float* endT   = (const float*)d_in[6];
  const float* T      = (const float*)d_in[7];

  float* out    = (float*)d_out;
  float* logits = out + 1;          // output 1 lives right after the scalar loss
  float* Mws    = (float*)d_ws;     // 32*16*169 floats = 346 KB

  hipMemsetAsync(d_out, 0, sizeof(float), stream);  // loss accumulator
  k_logits<<<BSc / RPB, RPB, 0, stream>>>(hs, W, bias, logits);
  k_chunks<<<Bc * NCHUNK, 256, 0, stream>>>(logits, amask, T, Mws);
  k_final <<<Bc, 64, 0, stream>>>(logits, amask, labels, startT, endT, T, Mws, out);
}

// Round 2
// 148.970 us; speedup vs baseline: 3.0409x; 3.0409x over previous
//
#include <hip/hip_runtime.h>
#include <math.h>

#define Lc 13
#define Hc 1024
#define Bc 32
#define Sc 2048
#define BSc (Bc*Sc)
#define CHUNK 128
#define NCHUNK 16

#define ROWS 64      // rows per block
#define PW   64      // panel width in h
#define NP   (Hc/PW) // 16 panels
#define THREADS 512  // 8 waves

#define INV_LN2 1.44269504088896340736f
#define LN2f    0.69314718055994530942f

#if __has_builtin(__builtin_amdgcn_exp2f)
#define EXP2F(x) __builtin_amdgcn_exp2f(x)
#else
#define EXP2F(x) exp2f(x)
#endif
#if __has_builtin(__builtin_amdgcn_logf)
#define LOG2F(x) __builtin_amdgcn_logf(x)
#else
#define LOG2F(x) log2f(x)
#endif

// ---------------------------------------------------------------------------
// Kernel A: logits[b,s,l] = sum_h hs[b,s,h]*W[l,h] + bias[l]
// 512 threads = 8 waves; block owns 64 rows; wave w owns h-slice {p*64+w*8*? }:
// per 64-h panel, wave w consumes f = w*16..w*16+15 split as 2 float4 (j=0,1
// gives f=w*8+j*4 per j over two slots => slots 2w,2w+1 of 16). H split across
// waves -> 8192 waves total (8/SIMD). Double-buffered panels, global_load_lds
// with inverse-swizzled SOURCE (G21), swizzled ds_read (conflict-free-ish).
// W reads are wave-uniform (readfirstlane on wave id) -> s_load_dwordx4.
// Per-wave partial acc[13] reduced through LDS at the end.
// ---------------------------------------------------------------------------
__global__ __launch_bounds__(THREADS, 8)
void k_logits(const float* __restrict__ A, const float* __restrict__ W,
              const float* __restrict__ bias, float* __restrict__ out) {
  __shared__ float buf[2][ROWS * PW];   // 2 x 16 KB
  const int tid = threadIdx.x;
  const int ln  = tid & 63;
  const int wu  = __builtin_amdgcn_readfirstlane(tid >> 6);  // wave id, SGPR
  const int rowBase = blockIdx.x * ROWS;

  float acc[Lc];
#pragma unroll
  for (int l = 0; l < Lc; ++l) acc[l] = 0.f;

  // stage panel p into buf[bsel]: LDS linear, source pre-inverse-swizzled
  auto stage = [&](int p, int bsel) {
#pragma unroll
    for (int i = 0; i < 2; ++i) {
      int slot = wu * 128 + i * 64 + ln;       // 16B slot, 16 slots/row
      int row  = slot >> 4;
      int c    = slot & 15;
      // stored h for slot c of row: wnd*32 + ((c&7)^(row&7))*4
      int h = ((c & 8) << 2) + ((((c & 7) ^ (row & 7))) << 2);
      const float* gp = A + (size_t)(rowBase + row) * Hc + (size_t)p * PW + h;
      float* lp = &buf[bsel][(wu * 128 + i * 64) * 4];   // wave-uniform base
      __builtin_amdgcn_global_load_lds(
          (const __attribute__((address_space(1))) void*)gp,
          (__attribute__((address_space(3))) void*)lp, 16, 0, 0);
    }
  };

  stage(0, 0);
  for (int p = 0; p < NP; ++p) {
    const int cur = p & 1;
    __syncthreads();                       // buf[cur] ready; buf[cur^1] free
    if (p + 1 < NP) stage(p + 1, cur ^ 1); // prefetch next panel
    const int row = ln;
#pragma unroll
    for (int j = 0; j < 2; ++j) {
      int f = wu * 8 + j * 4;              // h offset within panel, [0,64)
      int addr = row * PW + (f & 32) + (((((f >> 2) & 7) ^ (row & 7))) << 2);
      float4 a = *(const float4*)&buf[cur][addr];
#pragma unroll
      for (int l = 0; l < Lc; ++l) {
        const float4 wv = *(const float4*)(W + (size_t)l * Hc + (size_t)p * PW + f);
        acc[l] += a.x * wv.x + a.y * wv.y + a.z * wv.z + a.w * wv.w;
      }
    }
  }

  // reduce 8 per-wave partials through LDS (reuse buf; 8*64*13*4B = 26.6 KB)
  __syncthreads();                          // all compute done before overwrite
  float* part = &buf[0][0];
#pragma unroll
  for (int l = 0; l < Lc; ++l) part[(wu * 64 + ln) * Lc + l] = acc[l];
  __syncthreads();
  for (int o = tid; o < ROWS * Lc; o += THREADS) {
    int l = o % Lc;
    float s = bias[l];
#pragma unroll
    for (int ww = 0; ww < 8; ++ww) s += part[ww * (64 * Lc) + o];
    out[(size_t)rowBase * Lc + o] = s;
  }
}

// ---------------------------------------------------------------------------
// Kernel B: per (batch, chunk) 13x13 log-semiring transfer matrix.
// ---------------------------------------------------------------------------
__global__ void k_chunks(const float* __restrict__ logits, const int* __restrict__ mask,
                         const float* __restrict__ T, float* __restrict__ Mout) {
  const int bp = blockIdx.x;
  const int b  = bp >> 4;       // NCHUNK == 16
  const int p  = bp & 15;
  const int tid = threadIdx.x;
  const int g = tid >> 4;
  const int k = tid & 15;
  const int kk = (k < 13) ? k : 0;
  const int gg = (g < 13) ? g : 0;
  const bool active = (g < 13) && (k < 13);

  float Tc[13];   // column k of T, log2 domain
#pragma unroll
  for (int j = 0; j < 13; ++j) Tc[j] = T[j * 13 + kk] * INV_LN2;

  const int t0 = 1 + p * CHUNK;
  const int t1 = min(t0 + CHUNK, Sc);
  const size_t lbase = (size_t)b * Sc;

  float e0 = logits[(lbase + t0) * Lc + kk] * INV_LN2;
  int   m0 = mask[lbase + t0];
  float Tik = T[gg * 13 + kk] * INV_LN2;
  float M = m0 ? (Tik + e0) : ((g == k) ? 0.f : -1e30f);

  for (int t = t0 + 1; t < t1; ++t) {
    float e  = logits[(lbase + t) * Lc + kk] * INV_LN2;
    int   mk = mask[lbase + t];
    float v[13];
#pragma unroll
    for (int j = 0; j < 13; ++j) v[j] = __shfl(M, j, 16) + Tc[j];
    float m01 = fmaxf(v[0], v[1]),  m23 = fmaxf(v[2], v[3]);
    float m45 = fmaxf(v[4], v[5]),  m67 = fmaxf(v[6], v[7]);
    float m89 = fmaxf(v[8], v[9]),  mab = fmaxf(v[10], v[11]);
    float mx = fmaxf(fmaxf(fmaxf(m01, m23), fmaxf(m45, m67)),
                     fmaxf(fmaxf(m89, mab), v[12]));
    float e0s = EXP2F(v[0] - mx) + EXP2F(v[1] - mx);
    float e1s = EXP2F(v[2] - mx) + EXP2F(v[3] - mx);
    float e2s = EXP2F(v[4] - mx) + EXP2F(v[5] - mx);
    float e3s = EXP2F(v[6] - mx) + EXP2F(v[7] - mx);
    float e4s = EXP2F(v[8] - mx) + EXP2F(v[9] - mx);
    float e5s = EXP2F(v[10] - mx) + EXP2F(v[11] - mx);
    float s = ((e0s + e1s) + (e2s + e3s)) + ((e4s + e5s) + EXP2F(v[12] - mx));
    float nM = e + mx + LOG2F(s);
    M = mk ? nM : M;
  }
  if (active) Mout[(size_t)bp * 169 + g * 13 + k] = M;
}

// ---------------------------------------------------------------------------
// Kernel C: per batch: combine chunk matrices -> denominator; numerator; loss.
// ---------------------------------------------------------------------------
__global__ void k_final(const float* __restrict__ logits, const int* __restrict__ mask,
                        const int* __restrict__ labels, const float* __restrict__ startT,
                        const float* __restrict__ endT, const float* __restrict__ T,
                        const float* __restrict__ Mws, float* __restrict__ out0) {
  const int b = blockIdx.x;
  const int lane = threadIdx.x;
  const int kk = (lane < 13) ? lane : 0;
  const size_t lbase = (size_t)b * Sc;

  // ---- denominator (log2 domain) ----
  float v = (startT[kk] + logits[lbase * Lc + kk]) * INV_LN2;
  for (int p = 0; p < NCHUNK; ++p) {
    const float* Mp = Mws + (size_t)(b * NCHUNK + p) * 169;
    float a[13];
#pragma unroll
    for (int j = 0; j < 13; ++j) a[j] = __shfl(v, j, 64) + Mp[j * 13 + kk];
    float mx = a[0];
#pragma unroll
    for (int j = 1; j < 13; ++j) mx = fmaxf(mx, a[j]);
    float s = 0.f;
#pragma unroll
    for (int j = 0; j < 13; ++j) s += EXP2F(a[j] - mx);
    v = mx + LOG2F(s);
  }
  float x = (lane < 13) ? (v + endT[kk] * INV_LN2) : -1e30f;
  float mx = x;
#pragma unroll
  for (int off = 1; off < 16; off <<= 1) mx = fmaxf(mx, __shfl_xor(mx, off, 16));
  float sx = EXP2F(x - mx);
#pragma unroll
  for (int off = 1; off < 16; off <<= 1) sx += __shfl_xor(sx, off, 16);
  float den = (mx + LOG2F(sx)) * LN2f;   // valid on lanes 0..15; use lane 0

  // ---- numerator ----
  float np = 0.f;
  int   sl = 0;
  for (int t = lane; t < Sc; t += 64) {
    int mk = mask[lbase + t];
    sl += mk;
    int tg = labels[lbase + t];
    float em = logits[(lbase + t) * Lc + tg];
    if (t == 0) {
      np += startT[tg] + em;
    } else if (mk) {
      np += T[labels[lbase + t - 1] * 13 + tg] + em;
    }
  }
#pragma unroll
  for (int off = 32; off; off >>= 1) {
    np += __shfl_xor(np, off, 64);
    sl += __shfl_xor(sl, off, 64);
  }
  if (lane == 0) {
    int lastTag = labels[lbase + sl - 1];
    float num = np + endT[lastTag];
    float llh = num - den;
    atomicAdd(out0, -llh * (1.0f / Bc));
  }
}

extern "C" void kernel_launch(void* const* d_in, const int* in_sizes, int n_in,
                              void* d_out, int out_size, void* d_ws, size_t ws_size,
                              hipStream_t stream) {
  const float* hs     = (const float*)d_in[0];
  const int*   amask  = (const int*)d_in[1];
  const int*   labels = (const int*)d_in[2];
  const float* W      = (const float*)d_in[3];
  const float* bias   = (const float*)d_in[4];
  const float* startT = (const float*)d_in[5];
  const float* endT   = (const float*)d_in[6];
  const float* T      = (const float*)d_in[7];

  float* out    = (float*)d_out;
  float* logits = out + 1;          // output 1 lives right after the scalar loss
  float* Mws    = (float*)d_ws;     // 32*16*169 floats = 346 KB

  hipMemsetAsync(d_out, 0, sizeof(float), stream);  // loss accumulator
  k_logits<<<BSc / ROWS, THREADS, 0, stream>>>(hs, W, bias, logits);
  k_chunks<<<Bc * NCHUNK, 256, 0, stream>>>(logits, amask, T, Mws);
  k_final <<<Bc, 64, 0, stream>>>(logits, amask, labels, startT, endT, T, Mws, out);
}

// Round 3
// 127.630 us; speedup vs baseline: 3.5493x; 1.1672x over previous
//
#include <hip/hip_runtime.h>
#include <math.h>

#define Lc 13
#define Hc 1024
#define Bc 32
#define Sc 2048
#define BSc (Bc*Sc)
#define CHUNK 128
#define NCHUNK 16
#define NBLK (Bc*NCHUNK)   // 512 chunk blocks

#define ROWS 64      // rows per block (k_logits)
#define PW   64      // panel width in h
#define NP   (Hc/PW) // 16 panels
#define THREADS 512  // 8 waves

#define INV_LN2 1.44269504088896340736f
#define LN2f    0.69314718055994530942f

#if __has_builtin(__builtin_amdgcn_exp2f)
#define EXP2F(x) __builtin_amdgcn_exp2f(x)
#else
#define EXP2F(x) exp2f(x)
#endif
#if __has_builtin(__builtin_amdgcn_logf)
#define LOG2F(x) __builtin_amdgcn_logf(x)
#else
#define LOG2F(x) log2f(x)
#endif

// ---------------------------------------------------------------------------
// Kernel A (unchanged from round 2): logits = hs @ W^T + b
// 512 threads = 8 waves; 64 rows/block; h split across waves; LDS-staged A via
// global_load_lds (inverse-swizzled source, G21); W via wave-uniform s_loads.
// ---------------------------------------------------------------------------
__global__ __launch_bounds__(THREADS, 8)
void k_logits(const float* __restrict__ A, const float* __restrict__ W,
              const float* __restrict__ bias, float* __restrict__ out) {
  __shared__ float buf[2][ROWS * PW];   // 2 x 16 KB
  const int tid = threadIdx.x;
  const int ln  = tid & 63;
  const int wu  = __builtin_amdgcn_readfirstlane(tid >> 6);  // wave id, SGPR
  const int rowBase = blockIdx.x * ROWS;

  float acc[Lc];
#pragma unroll
  for (int l = 0; l < Lc; ++l) acc[l] = 0.f;

  auto stage = [&](int p, int bsel) {
#pragma unroll
    for (int i = 0; i < 2; ++i) {
      int slot = wu * 128 + i * 64 + ln;       // 16B slot, 16 slots/row
      int row  = slot >> 4;
      int c    = slot & 15;
      int h = ((c & 8) << 2) + ((((c & 7) ^ (row & 7))) << 2);
      const float* gp = A + (size_t)(rowBase + row) * Hc + (size_t)p * PW + h;
      float* lp = &buf[bsel][(wu * 128 + i * 64) * 4];   // wave-uniform base
      __builtin_amdgcn_global_load_lds(
          (const __attribute__((address_space(1))) void*)gp,
          (__attribute__((address_space(3))) void*)lp, 16, 0, 0);
    }
  };

  stage(0, 0);
  for (int p = 0; p < NP; ++p) {
    const int cur = p & 1;
    __syncthreads();
    if (p + 1 < NP) stage(p + 1, cur ^ 1);
    const int row = ln;
#pragma unroll
    for (int j = 0; j < 2; ++j) {
      int f = wu * 8 + j * 4;
      int addr = row * PW + (f & 32) + (((((f >> 2) & 7) ^ (row & 7))) << 2);
      float4 a = *(const float4*)&buf[cur][addr];
#pragma unroll
      for (int l = 0; l < Lc; ++l) {
        const float4 wv = *(const float4*)(W + (size_t)l * Hc + (size_t)p * PW + f);
        acc[l] += a.x * wv.x + a.y * wv.y + a.z * wv.z + a.w * wv.w;
      }
    }
  }

  __syncthreads();
  float* part = &buf[0][0];
#pragma unroll
  for (int l = 0; l < Lc; ++l) part[(wu * 64 + ln) * Lc + l] = acc[l];
  __syncthreads();
  for (int o = tid; o < ROWS * Lc; o += THREADS) {
    int l = o % Lc;
    float s = bias[l];
#pragma unroll
    for (int ww = 0; ww < 8; ++ww) s += part[ww * (64 * Lc) + o];
    out[(size_t)rowBase * Lc + o] = s;
  }
}

// ---------------------------------------------------------------------------
// Kernel B: per (batch, chunk) 13x13 transfer matrix, LINEAR domain.
// P = 2^(M - off); U[j,k] = e^T[j,k]. Step: P'[i,k] = 2^e2[k] * sum_j P[i,j]U[j,k]
// (13 shfl + 13 fma + 1 exp2, vs 13 exp2 + log2 in log domain).
// Renorm every 8 steps via exponent extraction (invariant M = log2 P + off).
// Wave 0 additionally computes the chunk's numerator partial + mask count.
// ---------------------------------------------------------------------------
__global__ void k_chunks(const float* __restrict__ logits, const int* __restrict__ mask,
                         const int* __restrict__ labels, const float* __restrict__ T,
                         float* __restrict__ Mout, float* __restrict__ numpart,
                         float* __restrict__ cntpart) {
  const int bp = blockIdx.x;
  const int b  = bp >> 4;       // NCHUNK == 16
  const int p  = bp & 15;
  const int tid = threadIdx.x;
  const int g = tid >> 4;
  const int k = tid & 15;
  const int kk = (k < 13) ? k : 0;
  const int gg = (g < 13) ? g : 0;
  const bool active = (g < 13) && (k < 13);
  const size_t lbase = (size_t)b * Sc;
  const int t0 = 1 + p * CHUNK;
  const int t1 = min(t0 + CHUNK, Sc);

  float U[13];   // column kk of exp(T)
#pragma unroll
  for (int j = 0; j < 13; ++j) U[j] = EXP2F(T[j * 13 + kk] * INV_LN2);

  float e0 = logits[(lbase + t0) * Lc + kk] * INV_LN2;
  int   m0 = mask[lbase + t0];
  float P = m0 ? EXP2F(T[gg * 13 + kk] * INV_LN2 + e0) : ((g == k) ? 1.f : 0.f);
  float off = 0.f;

  for (int t = t0 + 1; t < t1; ++t) {
    float e2 = logits[(lbase + t) * Lc + kk] * INV_LN2;
    int   mk = mask[lbase + t];
    float pj[13];
#pragma unroll
    for (int j = 0; j < 13; ++j) pj[j] = __shfl(P, j, 16);
    float s0 = pj[0] * U[0];  s0 = fmaf(pj[4],  U[4],  s0);
    s0 = fmaf(pj[8],  U[8],  s0);  s0 = fmaf(pj[12], U[12], s0);
    float s1 = pj[1] * U[1];  s1 = fmaf(pj[5],  U[5],  s1);  s1 = fmaf(pj[9],  U[9],  s1);
    float s2 = pj[2] * U[2];  s2 = fmaf(pj[6],  U[6],  s2);  s2 = fmaf(pj[10], U[10], s2);
    float s3 = pj[3] * U[3];  s3 = fmaf(pj[7],  U[7],  s3);  s3 = fmaf(pj[11], U[11], s3);
    float s = (s0 + s1) + (s2 + s3);
    float Pn = EXP2F(e2) * s;
    P = mk ? Pn : P;
    if (((t - t0) & 7) == 0) {   // renorm: keep row max in [1,2)
      float mx = P;
#pragma unroll
      for (int o = 1; o < 16; o <<= 1) mx = fmaxf(mx, __shfl_xor(mx, o, 16));
      unsigned eb = (__float_as_uint(mx) >> 23) & 255u;
      float scale = __uint_as_float((254u - eb) << 23);   // 2^(127-eb)
      P *= scale;
      off += (float)((int)eb - 127);
    }
  }
  if (active) Mout[(size_t)bp * 169 + g * 13 + k] = (P > 0.f) ? (LOG2F(P) + off) : -1e30f;

  // ---- numerator partial for this chunk's tokens [t0, t1) ----
  if (tid < 64) {
    float np = 0.f; int cnt = 0;
    for (int t = t0 + tid; t < t1; t += 64) {
      int mk = mask[lbase + t];
      if (mk) {
        int tg = labels[lbase + t];
        int pg = labels[lbase + t - 1];
        np += T[pg * 13 + tg] + logits[(lbase + t) * Lc + tg];
        cnt += 1;
      }
    }
#pragma unroll
    for (int o = 1; o < 64; o <<= 1) {
      np  += __shfl_xor(np, o, 64);
      cnt += __shfl_xor(cnt, o, 64);
    }
    if (tid == 0) { numpart[bp] = np; cntpart[bp] = (float)cnt; }
  }
}

// ---------------------------------------------------------------------------
// Kernel C: per batch: combine 16 chunk matrices (log2 domain) -> denominator;
// assemble numerator from partials; atomicAdd loss.
// ---------------------------------------------------------------------------
__global__ void k_final(const float* __restrict__ logits, const int* __restrict__ mask,
                        const int* __restrict__ labels, const float* __restrict__ startT,
                        const float* __restrict__ endT, const float* __restrict__ Mws,
                        const float* __restrict__ numpart, const float* __restrict__ cntpart,
                        float* __restrict__ out0) {
  const int b = blockIdx.x;
  const int lane = threadIdx.x;
  const int kk = (lane < 13) ? lane : 0;
  const size_t lbase = (size_t)b * Sc;

  // ---- denominator (log2 domain) ----
  float v = (startT[kk] + logits[lbase * Lc + kk]) * INV_LN2;
  for (int p = 0; p < NCHUNK; ++p) {
    const float* Mp = Mws + (size_t)(b * NCHUNK + p) * 169;
    float a[13];
#pragma unroll
    for (int j = 0; j < 13; ++j) a[j] = __shfl(v, j, 64) + Mp[j * 13 + kk];
    float mx = a[0];
#pragma unroll
    for (int j = 1; j < 13; ++j) mx = fmaxf(mx, a[j]);
    float s = 0.f;
#pragma unroll
    for (int j = 0; j < 13; ++j) s += EXP2F(a[j] - mx);
    v = mx + LOG2F(s);
  }
  float x = (lane < 13) ? (v + endT[kk] * INV_LN2) : -1e30f;
  float mx = x;
#pragma unroll
  for (int off = 1; off < 16; off <<= 1) mx = fmaxf(mx, __shfl_xor(mx, off, 16));
  float sx = EXP2F(x - mx);
#pragma unroll
  for (int off = 1; off < 16; off <<= 1) sx += __shfl_xor(sx, off, 16);
  float den = (mx + LOG2F(sx)) * LN2f;   // valid on lanes 0..15

  // ---- numerator from chunk partials (lanes 0..15) ----
  float np = 0.f, cs = 0.f;
  if (lane < NCHUNK) { np = numpart[b * NCHUNK + lane]; cs = cntpart[b * NCHUNK + lane]; }
#pragma unroll
  for (int o = 1; o < 16; o <<= 1) {
    np += __shfl_xor(np, o, 16);
    cs += __shfl_xor(cs, o, 16);
  }
  if (lane == 0) {
    int lab0 = labels[lbase];
    int seqlen = mask[lbase] + (int)(cs + 0.5f);
    int lastTag = labels[lbase + seqlen - 1];
    float num = startT[lab0] + logits[lbase * Lc + lab0] + np + endT[lastTag];
    float llh = num - den;
    atomicAdd(out0, -llh * (1.0f / Bc));
  }
}

extern "C" void kernel_launch(void* const* d_in, const int* in_sizes, int n_in,
                              void* d_out, int out_size, void* d_ws, size_t ws_size,
                              hipStream_t stream) {
  const float* hs     = (const float*)d_in[0];
  const int*   amask  = (const int*)d_in[1];
  const int*   labels = (const int*)d_in[2];
  const float* W      = (const float*)d_in[3];
  const float* bias   = (const float*)d_in[4];
  const float* startT = (const float*)d_in[5];
  const float* endT   = (const float*)d_in[6];
  const float* T      = (const float*)d_in[7];

  float* out    = (float*)d_out;
  float* logits = out + 1;            // output 1 follows the scalar loss
  float* Mws    = (float*)d_ws;       // 512*169 floats = 346 KB
  float* numpart = Mws + (size_t)NBLK * 169;
  float* cntpart = numpart + NBLK;    // total ~350 KB of ws

  hipMemsetAsync(d_out, 0, sizeof(float), stream);  // loss accumulator
  k_logits<<<BSc / ROWS, THREADS, 0, stream>>>(hs, W, bias, logits);
  k_chunks<<<NBLK, 256, 0, stream>>>(logits, amask, labels, T, Mws, numpart, cntpart);
  k_final <<<Bc, 64, 0, stream>>>(logits, amask, labels, startT, endT, Mws, numpart, cntpart, out);
}